// Round 1
// 920.303 us; speedup vs baseline: 1.2808x; 1.2808x over previous
//
#include <hip/hip_runtime.h>
#include <stdint.h>

#define P_MOD       2013265921u   // 15*2^27 + 1
#define TWO32_MOD_P 268435454u    // 2^32 mod P

__device__ __forceinline__ uint32_t umin32(uint32_t a, uint32_t b) { return a < b ? a : b; }

// Least nonnegative residue mod P of the INT32 (two's-complement) interpretation
// of z (numpy int32 wraparound + numpy divisor-sign `% P`).
// min-idiom: r = min(z, z-P) picks z-P iff z>=P (underflow makes z-P huge otherwise).
// z < 2^32 < 3P so two conditional subtracts reduce; sign bit subtracts 2^32 mod P.
__device__ __forceinline__ uint32_t wrapmod(uint32_t z) {
    uint32_t r = umin32(z, z - P_MOD);
    r = umin32(r, r - P_MOD);
    uint32_t adj = (uint32_t)((int32_t)z >> 31) & TWO32_MOD_P;
    uint32_t s = r - adj;                 // in (-P, P) as int; wraps if negative
    return umin32(s, s + P_MOD);
}

// emulate numpy int32: (a * b) wrapped to 32 bits, then % P
__device__ __forceinline__ uint32_t mulmod_wrap(uint32_t a, uint32_t b) {
    return wrapmod(a * b);                // unsigned mul wraps mod 2^32 = lo32
}

// ---------------------------------------------------------------------------
// K1: tiled bit-reversal permute (natural -> logical layout) + coset pre-scale
//     + stages 1..6 (pairs within p-bits 0..5 = the c dimension of the tile).
// Tile: p = u(6) * 2^(logn-6) + w * 64 + c(6), fixed w per block.
// src = brev(p) = brev6(c)*2^(logn-6) + brevW(w)*64 + brev6(u):
//   for fixed c, u-sweep = 64 consecutive addresses -> 256B read runs.
// Writes: for fixed u, c-sweep = 64 consecutive addresses -> 256B write runs.
// ---------------------------------------------------------------------------
__global__ __launch_bounds__(256) void ntt_k1(
    const uint32_t* __restrict__ in,
    const uint32_t* __restrict__ tw,
    const uint32_t* __restrict__ itw,
    const uint32_t* __restrict__ cp,
    const int* __restrict__ f_intt,
    const int* __restrict__ f_coset,
    uint32_t* __restrict__ out,
    int logn)
{
    __shared__ uint32_t sh[64 * 65];      // [u][c], pitch 65: (u+c)%32 banks, 2-way max
    const int tid = threadIdx.x;
    const int w   = blockIdx.x;           // [0, 2^(logn-12))
    const long long base = (long long)blockIdx.y << logn;

    const int is_intt  = f_intt[0];
    const bool do_coset = (!is_intt) && (f_coset[0] != 0);
    const uint32_t* __restrict__ twsel = is_intt ? itw : tw;

    const uint32_t wrev = __brev((uint32_t)w) >> (32 - (logn - 12));

    // gather: per wave one 256B contiguous run (c fixed, s = lane)
    for (int it = 0; it < 16; ++it) {
        int c = (it << 2) | (tid >> 6);
        int s = tid & 63;
        uint32_t crev = __brev((uint32_t)c) >> 26;            // brev6(c)
        long long src = ((long long)crev << (logn - 6)) |
                        ((long long)wrev << 6) | (unsigned)s;
        uint32_t x = in[base + src];
        if (do_coset) x = mulmod_wrap(x, cp[src]);            // cp indexed by natural pos
        uint32_t u = __brev((uint32_t)s) >> 26;               // brev6(s)
        sh[u * 65 + c] = x;
    }
    __syncthreads();

    // stages 1..6: butterflies along c within each row u; j = p mod hs = c mod hs
    for (int pa = 1; pa <= 6; ++pa) {
        const int hs   = 1 << (pa - 1);
        const int twsh = logn - pa;
        for (int it = 0; it < 8; ++it) {
            int bf   = tid + it * 256;    // [0,2048): 64 rows x 32 c-butterflies
            int row  = bf >> 5;
            int cb   = bf & 31;
            int j    = cb & (hs - 1);
            int cblk = cb >> (pa - 1);
            int cu   = (cblk << pa) | j;
            int cv   = cu + hs;
            uint32_t u = sh[row * 65 + cu];
            uint32_t v = sh[row * 65 + cv];
            uint32_t t2 = mulmod_wrap(v, twsel[(uint32_t)j << twsh]);
            sh[row * 65 + cu] = wrapmod(u + t2);
            sh[row * 65 + cv] = wrapmod(u - t2);
        }
        __syncthreads();
    }

    // scatter to logical layout: per wave one 256B contiguous run (u fixed)
    for (int it = 0; it < 16; ++it) {
        int u = (it << 2) | (tid >> 6);
        int c = tid & 63;
        long long dst = ((long long)u << (logn - 6)) |
                        ((long long)w << 6) | (unsigned)c;
        out[base + dst] = sh[u * 65 + c];
    }
}

// ---------------------------------------------------------------------------
// K2: stages 7..13 (pairs within p-bits 6..12) on contiguous 8192-blocks of
// logical layout. Fully coalesced global IO; hs >= 64 so 64 consecutive lanes
// hit 64 consecutive LDS words -> zero bank conflicts. In-place (block-closed).
// ---------------------------------------------------------------------------
__global__ __launch_bounds__(256) void ntt_k2(
    const uint32_t* __restrict__ tw,
    const uint32_t* __restrict__ itw,
    const int* __restrict__ f_intt,
    uint32_t* __restrict__ data,
    int logn)
{
    __shared__ uint32_t sh[8192];
    const int tid = threadIdx.x;
    const long long base = ((long long)blockIdx.y << logn) +
                           ((long long)blockIdx.x << 13);
    const uint32_t* __restrict__ twsel = f_intt[0] ? itw : tw;

    for (int it = 0; it < 32; ++it) { int t = tid + it * 256; sh[t] = data[base + t]; }
    __syncthreads();

    for (int pa = 7; pa <= 13; ++pa) {
        const int hs   = 1 << (pa - 1);
        const int twsh = logn - pa;
        for (int it = 0; it < 16; ++it) {
            int bf  = tid + it * 256;     // 0..4095
            int j   = bf & (hs - 1);
            int blk = bf >> (pa - 1);
            int iu  = (blk << pa) | j;
            int iv  = iu + hs;
            uint32_t u = sh[iu];
            uint32_t v = sh[iv];
            uint32_t t2 = mulmod_wrap(v, twsel[(uint32_t)j << twsh]);
            sh[iu] = wrapmod(u + t2);
            sh[iv] = wrapmod(u - t2);
        }
        __syncthreads();
    }

    for (int it = 0; it < 32; ++it) { int t = tid + it * 256; data[base + t] = sh[t]; }
}

// ---------------------------------------------------------------------------
// K3: stages 14..22 (pairs within p-bits 13..21), in place. Tile: 512 strided
// (stride 2^13) x 32 contiguous lows -> 128B (full cache line) transactions.
// LDS [512][32] pitch 32: lanes sweep lo fast -> banks = lo, 2-way max (free).
// 512 threads, 64KB LDS (2 blocks/CU, 16 waves/CU).
// ---------------------------------------------------------------------------
__global__ __launch_bounds__(512) void ntt_k3(
    const uint32_t* __restrict__ tw,
    const uint32_t* __restrict__ itw,
    const uint32_t* __restrict__ icp,
    const int* __restrict__ f_intt,
    const int* __restrict__ f_coset,
    uint32_t* __restrict__ data,
    uint32_t ninv, int logn)
{
    __shared__ uint32_t sh[512 * 32];
    const int tid = threadIdx.x;
    const long long base = (long long)blockIdx.y << logn;
    const int lowbase = blockIdx.x * 32;

    const int is_intt  = f_intt[0];
    const int is_coset = f_coset[0];
    const uint32_t* __restrict__ twsel = is_intt ? itw : tw;

    for (int it = 0; it < 32; ++it) {
        int e  = tid + it * 512;
        int lo = e & 31;
        int s  = e >> 5;
        sh[(s << 5) | lo] = data[base + ((long long)s << 13) + lowbase + lo];
    }
    __syncthreads();

    for (int p = 0; p <= 8; ++p) {
        const int hs   = 1 << p;
        const int twsh = 8 - p;
        for (int it = 0; it < 16; ++it) {
            int bf   = tid + it * 512;    // 256 s-pairs x 32 lows
            int lo   = bf & 31;
            int sb   = bf >> 5;           // 0..255
            int sj   = sb & (hs - 1);
            int sblk = sb >> p;
            int su   = (sblk << (p + 1)) | sj;
            int sv   = su + hs;
            uint32_t u = sh[(su << 5) | lo];
            uint32_t v = sh[(sv << 5) | lo];
            uint32_t jg = (uint32_t)(lowbase + lo) + ((uint32_t)sj << 13);
            uint32_t t2 = mulmod_wrap(v, twsel[jg << twsh]);
            sh[(su << 5) | lo] = wrapmod(u + t2);
            sh[(sv << 5) | lo] = wrapmod(u - t2);
        }
        __syncthreads();
    }

    // store (+ INTT post-scales, wrap-correct)
    for (int it = 0; it < 32; ++it) {
        int e  = tid + it * 512;
        int lo = e & 31;
        int s  = e >> 5;
        uint32_t val = sh[(s << 5) | lo];
        long long gi = ((long long)s << 13) + lowbase + lo;
        if (is_intt) {
            val = mulmod_wrap(val, ninv);                    // * N^{-1}
            if (is_coset) val = mulmod_wrap(val, icp[gi]);   // * g^{-i}
        }
        data[base + gi] = val;
    }
}

extern "C" void kernel_launch(void* const* d_in, const int* in_sizes, int n_in,
                              void* d_out, int out_size, void* d_ws, size_t ws_size,
                              hipStream_t stream) {
    const uint32_t* in  = (const uint32_t*)d_in[0];
    const uint32_t* tw  = (const uint32_t*)d_in[1];
    const uint32_t* itw = (const uint32_t*)d_in[2];
    const uint32_t* cp  = (const uint32_t*)d_in[3];
    const uint32_t* icp = (const uint32_t*)d_in[4];
    // d_in[5] = bitrev (unused; computed via __brev on device)
    const int* f_intt  = (const int*)d_in[6];
    const int* f_coset = (const int*)d_in[7];

    const int N = in_sizes[5];            // bitrev has N entries
    const int B = in_sizes[0] / N;
    int logn = 0; while ((1 << logn) < N) ++logn;

    // N^{-1} mod P (host-side, exact)
    const unsigned long long P = 2013265921ull;
    unsigned long long b = (unsigned long long)N % P, e = P - 2, acc = 1;
    while (e) { if (e & 1) acc = acc * b % P; b = b * b % P; e >>= 1; }
    const uint32_t ninv = (uint32_t)acc;

    uint32_t* out = (uint32_t*)d_out;

    dim3 blk256(256);
    dim3 g1(N / 4096, B);                 // 64x64 tiles, one w per block
    ntt_k1<<<g1, blk256, 0, stream>>>(in, tw, itw, cp, f_intt, f_coset, out, logn);

    dim3 g2(N / 8192, B);
    ntt_k2<<<g2, blk256, 0, stream>>>(tw, itw, f_intt, out, logn);

    dim3 g3(8192 / 32, B);                // 256 lo-chunks of width 32
    ntt_k3<<<g3, dim3(512), 0, stream>>>(tw, itw, icp, f_intt, f_coset, out, ninv, logn);
}

// Round 2
// 682.296 us; speedup vs baseline: 1.7275x; 1.3488x over previous
//
#include <hip/hip_runtime.h>
#include <stdint.h>

#define P_MOD       2013265921u   // 15*2^27 + 1
#define TWO32_MOD_P 268435454u    // 2^32 mod P

__device__ __forceinline__ uint32_t umin32(uint32_t a, uint32_t b) { return a < b ? a : b; }

// Least nonnegative residue mod P of the INT32 (two's-complement) interpretation
// of z (numpy int32 wraparound + numpy divisor-sign `% P`).
// min-idiom: r = min(z, z-P) picks z-P iff z>=P (underflow makes z-P huge otherwise).
__device__ __forceinline__ uint32_t wrapmod(uint32_t z) {
    uint32_t r = umin32(z, z - P_MOD);
    r = umin32(r, r - P_MOD);
    uint32_t adj = (uint32_t)((int32_t)z >> 31) & TWO32_MOD_P;
    uint32_t s = r - adj;                 // in (-P, P) as int; wraps if negative
    return umin32(s, s + P_MOD);
}

// emulate numpy int32: (a * b) wrapped to 32 bits, then % P
__device__ __forceinline__ uint32_t mulmod_wrap(uint32_t a, uint32_t b) {
    return wrapmod(a * b);                // unsigned mul wraps mod 2^32 = lo32
}

// ---------------------------------------------------------------------------
// K0: pack per-stage twiddle tables for K2 (stages 7..13) into workspace.
// Layout: stage pa at base (2^(pa-1) - 64), entries j in [0, 2^(pa-1)):
//   ptw[base+j] = twsel[j << (logn-pa)].  Total 8128 words (32 KB).
// K2 then reads twiddles fully coalesced (lanes sweep j consecutively).
// ---------------------------------------------------------------------------
__global__ __launch_bounds__(256) void ntt_pack(
    const uint32_t* __restrict__ tw,
    const uint32_t* __restrict__ itw,
    const int* __restrict__ f_intt,
    uint32_t* __restrict__ ptw, int logn)
{
    int idx = blockIdx.x * 256 + threadIdx.x;
    if (idx >= 8128) return;
    const uint32_t* __restrict__ twsel = f_intt[0] ? itw : tw;
    uint32_t v = (uint32_t)idx + 64u;     // in [2^(pa-1), 2^pa)
    int pm1 = 31 - __clz(v);              // pa-1
    int j   = (int)(v - (1u << pm1));
    int pa  = pm1 + 1;
    ptw[idx] = twsel[(uint32_t)j << (logn - pa)];
}

// ---------------------------------------------------------------------------
// K1: tiled bit-reversal permute (natural -> logical layout) + coset pre-scale
//     + stages 1..6. Tile: p = u(6)*2^(logn-6) + w*64 + c(6).
// Gather: thread loads uint4 (4 consecutive s for fixed c) -> 256B runs/wave.
// Scatter: thread stores uint4 (4 consecutive c for fixed u) -> 256B runs/wave.
// ---------------------------------------------------------------------------
__global__ __launch_bounds__(256) void ntt_k1(
    const uint32_t* __restrict__ in,
    const uint32_t* __restrict__ tw,
    const uint32_t* __restrict__ itw,
    const uint32_t* __restrict__ cp,
    const int* __restrict__ f_intt,
    const int* __restrict__ f_coset,
    uint32_t* __restrict__ out,
    int logn)
{
    __shared__ uint32_t sh[64 * 65];      // [u][c], pitch 65 (odd): 2-way max conflicts
    const int tid = threadIdx.x;
    const int w   = blockIdx.x;           // [0, 2^(logn-12))
    const long long base = (long long)blockIdx.y << logn;

    const int is_intt  = f_intt[0];
    const bool do_coset = (!is_intt) && (f_coset[0] != 0);
    const uint32_t* __restrict__ twsel = is_intt ? itw : tw;

    const uint32_t wrev = __brev((uint32_t)w) >> (32 - (logn - 12));

    // gather: uint4 per thread; s = 4*s4+k, u = brev6(s) = brev2(k)*16 + brev4(s4)
    const int s4 = tid & 15;
    const uint32_t ub = __brev((uint32_t)s4) >> 28;           // brev4(s4)
    for (int it = 0; it < 4; ++it) {
        int c = (it << 4) | (tid >> 4);
        uint32_t crev = __brev((uint32_t)c) >> 26;            // brev6(c)
        long long src = ((long long)crev << (logn - 6)) |
                        ((long long)wrev << 6) | (unsigned)(s4 << 2);
        uint4 x = *(const uint4*)(in + base + src);
        if (do_coset) {
            uint4 cv = *(const uint4*)(cp + src);             // cp indexed by natural pos
            x.x = mulmod_wrap(x.x, cv.x);
            x.y = mulmod_wrap(x.y, cv.y);
            x.z = mulmod_wrap(x.z, cv.z);
            x.w = mulmod_wrap(x.w, cv.w);
        }
        sh[(ub     ) * 65 + c] = x.x;     // k=0 -> u = ub
        sh[(ub + 32) * 65 + c] = x.y;     // k=1 -> u = ub+32
        sh[(ub + 16) * 65 + c] = x.z;     // k=2 -> u = ub+16
        sh[(ub + 48) * 65 + c] = x.w;     // k=3 -> u = ub+48
    }
    __syncthreads();

    // stages 1..6: butterflies along c within each row u; j = p mod hs = c mod hs
    for (int pa = 1; pa <= 6; ++pa) {
        const int hs   = 1 << (pa - 1);
        const int twsh = logn - pa;
        for (int it = 0; it < 8; ++it) {
            int bf   = tid + it * 256;    // [0,2048): 64 rows x 32 c-butterflies
            int row  = bf >> 5;
            int cb   = bf & 31;
            int j    = cb & (hs - 1);
            int cblk = cb >> (pa - 1);
            int cu   = (cblk << pa) | j;
            int cv   = cu + hs;
            uint32_t u = sh[row * 65 + cu];
            uint32_t v = sh[row * 65 + cv];
            uint32_t t2 = mulmod_wrap(v, twsel[(uint32_t)j << twsh]);
            sh[row * 65 + cu] = wrapmod(u + t2);
            sh[row * 65 + cv] = wrapmod(u - t2);
        }
        __syncthreads();
    }

    // scatter to logical layout: uint4 per thread (4 consecutive c, fixed u)
    for (int it = 0; it < 4; ++it) {
        int u  = (it << 4) | (tid >> 4);
        int cb = (tid & 15) << 2;
        uint4 x;
        x.x = sh[u * 65 + cb    ];
        x.y = sh[u * 65 + cb + 1];
        x.z = sh[u * 65 + cb + 2];
        x.w = sh[u * 65 + cb + 3];
        long long dst = ((long long)u << (logn - 6)) |
                        ((long long)w << 6) | (unsigned)cb;
        *(uint4*)(out + base + dst) = x;
    }
}

// ---------------------------------------------------------------------------
// K2: stages 7..13 on contiguous 8192-blocks of logical layout. 512 threads,
// 32 KB LDS -> 4 blocks/CU = 100% occupancy. uint4 global IO. Twiddles from
// packed table (coalesced); zero LDS bank conflicts (hs >= 64). In place.
// ---------------------------------------------------------------------------
__global__ __launch_bounds__(512) void ntt_k2(
    const uint32_t* __restrict__ tw,
    const uint32_t* __restrict__ itw,
    const int* __restrict__ f_intt,
    const uint32_t* __restrict__ ptw,     // packed stage twiddles (or nullptr)
    uint32_t* __restrict__ data,
    int logn)
{
    __shared__ uint32_t sh[8192];
    const int tid = threadIdx.x;
    const long long base = ((long long)blockIdx.y << logn) +
                           ((long long)blockIdx.x << 13);
    const uint32_t* __restrict__ twsel = f_intt[0] ? itw : tw;

    for (int it = 0; it < 4; ++it) {
        int t4 = tid + it * 512;
        ((uint4*)sh)[t4] = ((const uint4*)(data + base))[t4];
    }
    __syncthreads();

    for (int pa = 7; pa <= 13; ++pa) {
        const int hs    = 1 << (pa - 1);
        const int twsh  = logn - pa;
        const int pbase = hs - 64;
        for (int it = 0; it < 8; ++it) {
            int bf  = tid + it * 512;     // 0..4095
            int j   = bf & (hs - 1);
            int blk = bf >> (pa - 1);
            int iu  = (blk << pa) | j;
            int iv  = iu + hs;
            uint32_t u = sh[iu];
            uint32_t v = sh[iv];
            uint32_t wv = ptw ? ptw[pbase + j] : twsel[(uint32_t)j << twsh];
            uint32_t t2 = mulmod_wrap(v, wv);
            sh[iu] = wrapmod(u + t2);
            sh[iv] = wrapmod(u - t2);
        }
        __syncthreads();
    }

    for (int it = 0; it < 4; ++it) {
        int t4 = tid + it * 512;
        ((uint4*)(data + base))[t4] = ((const uint4*)sh)[t4];
    }
}

// ---------------------------------------------------------------------------
// K3: stages 14..22, in place. Tile: 512 strided (stride 2^13) x 32 lows.
// 1024 threads, 64 KB LDS -> 2 blocks x 16 waves = 100% occupancy.
// uint4 global IO (128B per 8-lane group = full cache lines).
// ---------------------------------------------------------------------------
__global__ __launch_bounds__(1024) void ntt_k3(
    const uint32_t* __restrict__ tw,
    const uint32_t* __restrict__ itw,
    const uint32_t* __restrict__ icp,
    const int* __restrict__ f_intt,
    const int* __restrict__ f_coset,
    uint32_t* __restrict__ data,
    uint32_t ninv, int logn)
{
    __shared__ uint32_t sh[512 * 32];
    const int tid = threadIdx.x;
    const long long base = (long long)blockIdx.y << logn;
    const int lowbase = blockIdx.x * 32;

    const int is_intt  = f_intt[0];
    const int is_coset = f_coset[0];
    const uint32_t* __restrict__ twsel = is_intt ? itw : tw;

    for (int it = 0; it < 4; ++it) {
        int e4  = tid + it * 1024;        // uint4 index, 0..4095
        int lo4 = e4 & 7;
        int s   = e4 >> 3;
        *(uint4*)&sh[(s << 5) | (lo4 << 2)] =
            *(const uint4*)(data + base + ((long long)s << 13) + lowbase + (lo4 << 2));
    }
    __syncthreads();

    for (int p = 0; p <= 8; ++p) {
        const int hs   = 1 << p;
        const int twsh = 8 - p;
        for (int it = 0; it < 8; ++it) {
            int bf   = tid + it * 1024;   // 256 s-pairs x 32 lows
            int lo   = bf & 31;
            int sb   = bf >> 5;           // 0..255
            int sj   = sb & (hs - 1);
            int sblk = sb >> p;
            int su   = (sblk << (p + 1)) | sj;
            int sv   = su + hs;
            uint32_t u = sh[(su << 5) | lo];
            uint32_t v = sh[(sv << 5) | lo];
            uint32_t jg = (uint32_t)(lowbase + lo) + ((uint32_t)sj << 13);
            uint32_t t2 = mulmod_wrap(v, twsel[jg << twsh]);
            sh[(su << 5) | lo] = wrapmod(u + t2);
            sh[(sv << 5) | lo] = wrapmod(u - t2);
        }
        __syncthreads();
    }

    // store (+ INTT post-scales, wrap-correct)
    for (int it = 0; it < 4; ++it) {
        int e4  = tid + it * 1024;
        int lo4 = e4 & 7;
        int s   = e4 >> 3;
        uint4 val = *(const uint4*)&sh[(s << 5) | (lo4 << 2)];
        long long gi = ((long long)s << 13) + lowbase + (lo4 << 2);
        if (is_intt) {
            val.x = mulmod_wrap(val.x, ninv);
            val.y = mulmod_wrap(val.y, ninv);
            val.z = mulmod_wrap(val.z, ninv);
            val.w = mulmod_wrap(val.w, ninv);
            if (is_coset) {
                uint4 ic = *(const uint4*)(icp + gi);
                val.x = mulmod_wrap(val.x, ic.x);
                val.y = mulmod_wrap(val.y, ic.y);
                val.z = mulmod_wrap(val.z, ic.z);
                val.w = mulmod_wrap(val.w, ic.w);
            }
        }
        *(uint4*)(data + base + gi) = val;
    }
}

extern "C" void kernel_launch(void* const* d_in, const int* in_sizes, int n_in,
                              void* d_out, int out_size, void* d_ws, size_t ws_size,
                              hipStream_t stream) {
    const uint32_t* in  = (const uint32_t*)d_in[0];
    const uint32_t* tw  = (const uint32_t*)d_in[1];
    const uint32_t* itw = (const uint32_t*)d_in[2];
    const uint32_t* cp  = (const uint32_t*)d_in[3];
    const uint32_t* icp = (const uint32_t*)d_in[4];
    // d_in[5] = bitrev (unused; computed via __brev on device)
    const int* f_intt  = (const int*)d_in[6];
    const int* f_coset = (const int*)d_in[7];

    const int N = in_sizes[5];            // bitrev has N entries
    const int B = in_sizes[0] / N;
    int logn = 0; while ((1 << logn) < N) ++logn;

    // N^{-1} mod P (host-side, exact)
    const unsigned long long P = 2013265921ull;
    unsigned long long b = (unsigned long long)N % P, e = P - 2, acc = 1;
    while (e) { if (e & 1) acc = acc * b % P; b = b * b % P; e >>= 1; }
    const uint32_t ninv = (uint32_t)acc;

    uint32_t* out = (uint32_t*)d_out;

    // packed twiddles for K2 (32 KB in workspace; fallback to direct if absent)
    uint32_t* ptw = (ws_size >= 8128u * 4u) ? (uint32_t*)d_ws : nullptr;
    if (ptw) ntt_pack<<<dim3(32), dim3(256), 0, stream>>>(tw, itw, f_intt, ptw, logn);

    dim3 g1(N / 4096, B);                 // 64x64 tiles, one w per block
    ntt_k1<<<g1, dim3(256), 0, stream>>>(in, tw, itw, cp, f_intt, f_coset, out, logn);

    dim3 g2(N / 8192, B);
    ntt_k2<<<g2, dim3(512), 0, stream>>>(tw, itw, f_intt, ptw, out, logn);

    dim3 g3(8192 / 32, B);                // 256 lo-chunks of width 32
    ntt_k3<<<g3, dim3(1024), 0, stream>>>(tw, itw, icp, f_intt, f_coset, out, ninv, logn);
}

// Round 3
// 528.550 us; speedup vs baseline: 2.2300x; 1.2909x over previous
//
#include <hip/hip_runtime.h>
#include <stdint.h>

#define P_MOD       2013265921u   // 15*2^27 + 1  (= 2^31 - 2^27 + 1, "BabyBear")
#define TWO32_MOD_P 268435454u    // 2^32 mod P == 2^32 - 2P

__device__ __forceinline__ uint32_t umin32(uint32_t a, uint32_t b) { return a < b ? a : b; }

// W(z): least nonneg residue mod P of the int32 (two's-complement) interpretation
// of z (numpy int32 wrap + numpy `% P`).  t = z - sign*(2^32-2P) lands in [0,2P)
// for every z < 2^32, so a single conditional subtract finishes.  5 VALU ops.
__device__ __forceinline__ uint32_t wrapmod(uint32_t z) {
    uint32_t t = z - ((uint32_t)((int32_t)z >> 31) & TWO32_MOD_P);
    return umin32(t, t - P_MOD);
}

// numpy (u + t2) % P for u,t2 in [0,P): u+t2 < 2P < 2^32, wrapmod handles the
// int32 sign-wrap case exactly.
__device__ __forceinline__ uint32_t addmod_w(uint32_t u, uint32_t t2) {
    return wrapmod(u + t2);
}

// numpy (u - t2) % P for u,t2 in [0,P): difference is in (-P,P) as int32 (no
// overflow), so result = u-t2 (+P if negative).  3 VALU ops.
__device__ __forceinline__ uint32_t submod_w(uint32_t u, uint32_t t2) {
    uint32_t d = u - t2;
    return umin32(d, d + P_MOD);
}

// emulate numpy int32: (a * b) wrapped to 32 bits, then % P
__device__ __forceinline__ uint32_t mulmod_wrap(uint32_t a, uint32_t b) {
    return wrapmod(a * b);                // unsigned mul wraps mod 2^32 = lo32
}

// ---- Montgomery (R = 2^32): used ONLY to synthesize exact twiddle values ----
__host__ __device__ constexpr uint32_t compute_pinv_neg() {
    uint32_t x = 1u;                      // Newton: x -> x(2 - P*x) mod 2^32
    for (int i = 0; i < 5; ++i) x *= (2u - P_MOD * x);
    return 0u - x;                        // -P^{-1} mod 2^32
}
#define PINV_NEG (compute_pinv_neg())
constexpr uint32_t R2_MOD_P = (uint32_t)(((unsigned __int128)1 << 64) % P_MOD);

// montmul(a,b) = a*b*2^{-32} mod P, result in [0,P).  With a = wA*2^32 mod P
// (Montgomery form) this yields the EXACT table value wA*wB mod P.
__device__ __forceinline__ uint32_t montmul(uint32_t a, uint32_t b) {
    uint32_t lo = a * b;
    uint32_t hi = __umulhi(a, b);
    uint32_t m  = lo * PINV_NEG;
    uint32_t t  = hi + __umulhi(m, P_MOD) + (lo != 0u);
    return umin32(t, t - P_MOD);
}

// ---- non-temporal 16B load/store (keep streams out of L2/L3 retention) ----
typedef uint32_t u32x4 __attribute__((ext_vector_type(4)));
__device__ __forceinline__ uint4 nt_load4(const uint32_t* p) {
    u32x4 v = __builtin_nontemporal_load(reinterpret_cast<const u32x4*>(p));
    return make_uint4(v.x, v.y, v.z, v.w);
}
__device__ __forceinline__ void nt_store4(uint32_t* p, uint4 x) {
    u32x4 v = {x.x, x.y, x.z, x.w};
    __builtin_nontemporal_store(v, reinterpret_cast<u32x4*>(p));
}

// ---------------------------------------------------------------------------
// K0: pack per-stage twiddle tables for K2 (stages 7..13) into workspace.
// Layout: stage pa at base (2^(pa-1) - 64), entries j in [0, 2^(pa-1)):
//   ptw[base+j] = twsel[j << (logn-pa)].  8128 words; bases are 4-aligned so
//   K2 can read uint4.
// ---------------------------------------------------------------------------
__global__ __launch_bounds__(256) void ntt_pack(
    const uint32_t* __restrict__ tw,
    const uint32_t* __restrict__ itw,
    const int* __restrict__ f_intt,
    uint32_t* __restrict__ ptw, int logn)
{
    int idx = blockIdx.x * 256 + threadIdx.x;
    if (idx >= 8128) return;
    const uint32_t* __restrict__ twsel = f_intt[0] ? itw : tw;
    uint32_t v = (uint32_t)idx + 64u;     // in [2^(pa-1), 2^pa)
    int pm1 = 31 - __clz(v);              // pa-1
    int j   = (int)(v - (1u << pm1));
    int pa  = pm1 + 1;
    ptw[idx] = twsel[(uint32_t)j << (logn - pa)];
}

// ---------------------------------------------------------------------------
// K1: tiled bit-reversal permute (natural -> logical layout) + coset pre-scale
//     + stages 1..6. Tile: p = u(6)*2^(logn-6) + w*64 + c(6).
// ---------------------------------------------------------------------------
__global__ __launch_bounds__(256) void ntt_k1(
    const uint32_t* __restrict__ in,
    const uint32_t* __restrict__ tw,
    const uint32_t* __restrict__ itw,
    const uint32_t* __restrict__ cp,
    const int* __restrict__ f_intt,
    const int* __restrict__ f_coset,
    uint32_t* __restrict__ out,
    int logn)
{
    __shared__ uint32_t sh[64 * 65];      // [u][c], pitch 65 (odd): 2-way max conflicts
    const int tid = threadIdx.x;
    const int w   = blockIdx.x;           // [0, 2^(logn-12))
    const long long base = (long long)blockIdx.y << logn;

    const int is_intt  = f_intt[0];
    const bool do_coset = (!is_intt) && (f_coset[0] != 0);
    const uint32_t* __restrict__ twsel = is_intt ? itw : tw;

    const uint32_t wrev = __brev((uint32_t)w) >> (32 - (logn - 12));

    // gather: uint4 per thread; s = 4*s4+k, u = brev6(s) = brev2(k)*16 + brev4(s4)
    const int s4 = tid & 15;
    const uint32_t ub = __brev((uint32_t)s4) >> 28;           // brev4(s4)
    for (int it = 0; it < 4; ++it) {
        int c = (it << 4) | (tid >> 4);
        uint32_t crev = __brev((uint32_t)c) >> 26;            // brev6(c)
        long long src = ((long long)crev << (logn - 6)) |
                        ((long long)wrev << 6) | (unsigned)(s4 << 2);
        uint4 x = nt_load4(in + base + src);                  // read-once stream
        if (do_coset) {
            uint4 cv = nt_load4(cp + src);                    // cp indexed by natural pos
            x.x = mulmod_wrap(x.x, cv.x);
            x.y = mulmod_wrap(x.y, cv.y);
            x.z = mulmod_wrap(x.z, cv.z);
            x.w = mulmod_wrap(x.w, cv.w);
        }
        sh[(ub     ) * 65 + c] = x.x;     // k=0 -> u = ub
        sh[(ub + 32) * 65 + c] = x.y;     // k=1 -> u = ub+32
        sh[(ub + 16) * 65 + c] = x.z;     // k=2 -> u = ub+16
        sh[(ub + 48) * 65 + c] = x.w;     // k=3 -> u = ub+48
    }
    __syncthreads();

    // stages 1..6: butterflies along c within each row u; j = p mod hs = c mod hs
    for (int pa = 1; pa <= 6; ++pa) {
        const int hs   = 1 << (pa - 1);
        const int twsh = logn - pa;
        for (int it = 0; it < 8; ++it) {
            int bf   = tid + it * 256;    // [0,2048): 64 rows x 32 c-butterflies
            int row  = bf >> 5;
            int cb   = bf & 31;
            int j    = cb & (hs - 1);
            int cblk = cb >> (pa - 1);
            int cu   = (cblk << pa) | j;
            int cv   = cu + hs;
            uint32_t u = sh[row * 65 + cu];
            uint32_t v = sh[row * 65 + cv];
            uint32_t t2 = mulmod_wrap(v, twsel[(uint32_t)j << twsh]);
            sh[row * 65 + cu] = addmod_w(u, t2);
            sh[row * 65 + cv] = submod_w(u, t2);
        }
        __syncthreads();
    }

    // scatter to logical layout: uint4 per thread (4 consecutive c, fixed u)
    // (plain stores: K2 re-reads this -> keep cacheable)
    for (int it = 0; it < 4; ++it) {
        int u  = (it << 4) | (tid >> 4);
        int cb = (tid & 15) << 2;
        uint4 x;
        x.x = sh[u * 65 + cb    ];
        x.y = sh[u * 65 + cb + 1];
        x.z = sh[u * 65 + cb + 2];
        x.w = sh[u * 65 + cb + 3];
        long long dst = ((long long)u << (logn - 6)) |
                        ((long long)w << 6) | (unsigned)cb;
        *(uint4*)(out + base + dst) = x;
    }
}

// ---------------------------------------------------------------------------
// K2: stages 7..13 on contiguous 8192-blocks. hs >= 64 always -> quad
// butterflies: each thread does 4 consecutive j via ds_read_b128/write_b128,
// twiddles as uint4 from the packed table. 512 threads, 32 KB LDS.
// ---------------------------------------------------------------------------
__global__ __launch_bounds__(512, 8) void ntt_k2(
    const uint32_t* __restrict__ tw,
    const uint32_t* __restrict__ itw,
    const int* __restrict__ f_intt,
    const uint32_t* __restrict__ ptw,     // packed stage twiddles (or nullptr)
    uint32_t* __restrict__ data,
    int logn)
{
    alignas(16) __shared__ uint32_t sh[8192];
    const int tid = threadIdx.x;
    const long long base = ((long long)blockIdx.y << logn) +
                           ((long long)blockIdx.x << 13);
    const uint32_t* __restrict__ twsel = f_intt[0] ? itw : tw;

    for (int it = 0; it < 4; ++it) {
        int t4 = tid + it * 512;
        uint4 x = nt_load4(data + base + (t4 << 2));   // last read of K1 output
        ((uint4*)sh)[t4] = x;
    }
    __syncthreads();

    for (int pa = 7; pa <= 13; ++pa) {
        const int hs    = 1 << (pa - 1);  // >= 64
        const int twsh  = logn - pa;
        const int pbase = hs - 64;        // 4-aligned
        for (int it = 0; it < 2; ++it) {
            int q  = tid + it * 512;      // quad index, 0..1023
            int jq = q & ((hs >> 2) - 1);
            int blk= q >> (pa - 3);
            int j  = jq << 2;
            int iu = (blk << pa) | j;
            int iv = iu + hs;
            uint4 u = *(const uint4*)&sh[iu];
            uint4 v = *(const uint4*)&sh[iv];
            uint4 wv;
            if (ptw) {
                wv = *(const uint4*)&ptw[pbase + j];
            } else {
                wv.x = twsel[(uint32_t)(j    ) << twsh];
                wv.y = twsel[(uint32_t)(j + 1) << twsh];
                wv.z = twsel[(uint32_t)(j + 2) << twsh];
                wv.w = twsel[(uint32_t)(j + 3) << twsh];
            }
            uint32_t t0 = mulmod_wrap(v.x, wv.x);
            uint32_t t1 = mulmod_wrap(v.y, wv.y);
            uint32_t t2 = mulmod_wrap(v.z, wv.z);
            uint32_t t3 = mulmod_wrap(v.w, wv.w);
            uint4 ru = make_uint4(addmod_w(u.x, t0), addmod_w(u.y, t1),
                                  addmod_w(u.z, t2), addmod_w(u.w, t3));
            uint4 rv = make_uint4(submod_w(u.x, t0), submod_w(u.y, t1),
                                  submod_w(u.z, t2), submod_w(u.w, t3));
            *(uint4*)&sh[iu] = ru;
            *(uint4*)&sh[iv] = rv;
        }
        __syncthreads();
    }

    // plain stores: K3 re-reads this -> keep cacheable
    for (int it = 0; it < 4; ++it) {
        int t4 = tid + it * 512;
        ((uint4*)(data + base))[t4] = ((const uint4*)sh)[t4];
    }
}

// ---------------------------------------------------------------------------
// K3: stages 14..22 (local p=0..8), in place. Tile: 512 strided (stride 2^13)
// x 32 contiguous lows. Twiddles are SYNTHESIZED, not gathered:
//   w(sj,lo,p) = twsel[(sj*2^13+lo_g) << (8-p)]
//             = twsel[sj << (21-p)] * twsel[lo_g << (8-p)] mod P
// wA (511 entries, Montgomery form) + wB (9x32, plain) live in LDS; one
// montmul per butterfly reproduces the exact table value in [0,P).
// Stages p>=3 use quad (b128) butterflies over 4 consecutive lows.
// ---------------------------------------------------------------------------
__global__ __launch_bounds__(1024, 8) void ntt_k3(
    const uint32_t* __restrict__ tw,
    const uint32_t* __restrict__ itw,
    const uint32_t* __restrict__ icp,
    const int* __restrict__ f_intt,
    const int* __restrict__ f_coset,
    uint32_t* __restrict__ data,
    uint32_t ninv, int logn)
{
    alignas(16) __shared__ uint32_t sh[512 * 32];
    alignas(16) __shared__ uint32_t shB[9 * 32];  // wB[p][lo], plain form
    __shared__ uint32_t shA[511];                 // wA Montgomery form, base 2^p-1
    const int tid = threadIdx.x;
    const long long base = (long long)blockIdx.y << logn;
    const int lowbase = blockIdx.x * 32;

    const int is_intt  = f_intt[0];
    const int is_coset = f_coset[0];
    const uint32_t* __restrict__ twsel = is_intt ? itw : tw;

    // build twiddle-factor tables (once per block)
    if (tid < 511) {
        uint32_t v = (uint32_t)tid + 1u;          // in [1, 512)
        int p  = 31 - __clz(v);                   // stage 0..8
        int sj = (int)(v - (1u << p));
        uint32_t wa = twsel[(uint32_t)sj << (21 - p)];
        shA[tid] = montmul(wa, R2_MOD_P);         // -> wa * 2^32 mod P
    } else if (tid >= 512 && tid < 512 + 288) {
        int k = tid - 512, p = k >> 5, lo = k & 31;
        shB[k] = twsel[(uint32_t)(lowbase + lo) << (8 - p)];
    }

    for (int it = 0; it < 4; ++it) {
        int e4  = tid + it * 1024;                // uint4 index, 0..4095
        int lo4 = e4 & 7;
        int s   = e4 >> 3;
        uint4 x = nt_load4(data + base + ((long long)s << 13) + lowbase + (lo4 << 2));
        *(uint4*)&sh[(s << 5) | (lo4 << 2)] = x;
    }
    __syncthreads();

    // stages p=0..2: scalar butterflies (rows not contiguous -> b32, bank-free)
    for (int p = 0; p <= 2; ++p) {
        const int hs = 1 << p;
        for (int it = 0; it < 8; ++it) {
            int bf   = tid + it * 1024;   // 256 s-pairs x 32 lows
            int lo   = bf & 31;
            int sb   = bf >> 5;
            int sj   = sb & (hs - 1);
            int sblk = sb >> p;
            int su   = (sblk << (p + 1)) | sj;
            int sv   = su + hs;
            uint32_t u = sh[(su << 5) | lo];
            uint32_t v = sh[(sv << 5) | lo];
            uint32_t wv = montmul(shA[(hs - 1) + sj], shB[(p << 5) | lo]);
            uint32_t t2 = mulmod_wrap(v, wv);
            sh[(su << 5) | lo] = addmod_w(u, t2);
            sh[(sv << 5) | lo] = submod_w(u, t2);
        }
        __syncthreads();
    }

    // stages p=3..8: quad butterflies, 4 consecutive lows per thread (b128)
    for (int p = 3; p <= 8; ++p) {
        const int hs = 1 << p;
        for (int it = 0; it < 2; ++it) {
            int q    = tid + it * 1024;   // 0..2047: 256 s-pairs x 8 lo-quads
            int l4   = (q & 7) << 2;
            int sb   = q >> 3;
            int sj   = sb & (hs - 1);
            int sblk = sb >> p;
            int su   = (sblk << (p + 1)) | sj;
            int sv   = su + hs;
            uint4 u = *(const uint4*)&sh[(su << 5) | l4];
            uint4 v = *(const uint4*)&sh[(sv << 5) | l4];
            uint32_t wa = shA[(hs - 1) + sj];
            uint4 wb = *(const uint4*)&shB[(p << 5) | l4];
            uint32_t t0 = mulmod_wrap(v.x, montmul(wa, wb.x));
            uint32_t t1 = mulmod_wrap(v.y, montmul(wa, wb.y));
            uint32_t t2 = mulmod_wrap(v.z, montmul(wa, wb.z));
            uint32_t t3 = mulmod_wrap(v.w, montmul(wa, wb.w));
            uint4 ru = make_uint4(addmod_w(u.x, t0), addmod_w(u.y, t1),
                                  addmod_w(u.z, t2), addmod_w(u.w, t3));
            uint4 rv = make_uint4(submod_w(u.x, t0), submod_w(u.y, t1),
                                  submod_w(u.z, t2), submod_w(u.w, t3));
            *(uint4*)&sh[(su << 5) | l4] = ru;
            *(uint4*)&sh[(sv << 5) | l4] = rv;
        }
        __syncthreads();
    }

    // store (+ INTT post-scales, wrap-correct); final output -> non-temporal
    for (int it = 0; it < 4; ++it) {
        int e4  = tid + it * 1024;
        int lo4 = e4 & 7;
        int s   = e4 >> 3;
        uint4 val = *(const uint4*)&sh[(s << 5) | (lo4 << 2)];
        long long gi = ((long long)s << 13) + lowbase + (lo4 << 2);
        if (is_intt) {
            val.x = mulmod_wrap(val.x, ninv);
            val.y = mulmod_wrap(val.y, ninv);
            val.z = mulmod_wrap(val.z, ninv);
            val.w = mulmod_wrap(val.w, ninv);
            if (is_coset) {
                uint4 ic = *(const uint4*)(icp + gi);
                val.x = mulmod_wrap(val.x, ic.x);
                val.y = mulmod_wrap(val.y, ic.y);
                val.z = mulmod_wrap(val.z, ic.z);
                val.w = mulmod_wrap(val.w, ic.w);
            }
        }
        nt_store4(data + base + gi, val);
    }
}

extern "C" void kernel_launch(void* const* d_in, const int* in_sizes, int n_in,
                              void* d_out, int out_size, void* d_ws, size_t ws_size,
                              hipStream_t stream) {
    const uint32_t* in  = (const uint32_t*)d_in[0];
    const uint32_t* tw  = (const uint32_t*)d_in[1];
    const uint32_t* itw = (const uint32_t*)d_in[2];
    const uint32_t* cp  = (const uint32_t*)d_in[3];
    const uint32_t* icp = (const uint32_t*)d_in[4];
    // d_in[5] = bitrev (unused; computed via __brev on device)
    const int* f_intt  = (const int*)d_in[6];
    const int* f_coset = (const int*)d_in[7];

    const int N = in_sizes[5];            // bitrev has N entries
    const int B = in_sizes[0] / N;
    int logn = 0; while ((1 << logn) < N) ++logn;

    // N^{-1} mod P (host-side, exact)
    const unsigned long long P = 2013265921ull;
    unsigned long long b = (unsigned long long)N % P, e = P - 2, acc = 1;
    while (e) { if (e & 1) acc = acc * b % P; b = b * b % P; e >>= 1; }
    const uint32_t ninv = (uint32_t)acc;

    uint32_t* out = (uint32_t*)d_out;

    // packed twiddles for K2 (32 KB in workspace; fallback to direct if absent)
    uint32_t* ptw = (ws_size >= 8128u * 4u) ? (uint32_t*)d_ws : nullptr;
    if (ptw) ntt_pack<<<dim3(32), dim3(256), 0, stream>>>(tw, itw, f_intt, ptw, logn);

    dim3 g1(N / 4096, B);                 // 64x64 tiles, one w per block
    ntt_k1<<<g1, dim3(256), 0, stream>>>(in, tw, itw, cp, f_intt, f_coset, out, logn);

    dim3 g2(N / 8192, B);
    ntt_k2<<<g2, dim3(512), 0, stream>>>(tw, itw, f_intt, ptw, out, logn);

    dim3 g3(8192 / 32, B);                // 256 lo-chunks of width 32
    ntt_k3<<<g3, dim3(1024), 0, stream>>>(tw, itw, icp, f_intt, f_coset, out, ninv, logn);
}

// Round 4
// 471.983 us; speedup vs baseline: 2.4973x; 1.1198x over previous
//
#include <hip/hip_runtime.h>
#include <stdint.h>

#define P_MOD       2013265921u   // 15*2^27 + 1
#define TWO32_MOD_P 268435454u    // 2^32 mod P == 2^32 - 2P

__device__ __forceinline__ uint32_t umin32(uint32_t a, uint32_t b) { return a < b ? a : b; }

// W(z): least nonneg residue mod P of int32-interpretation of z (numpy int32
// wrap + numpy `% P`).  t = z - sign*(2^32-2P) lands in [0,2P); one cond-sub.
__device__ __forceinline__ uint32_t wrapmod(uint32_t z) {
    uint32_t t = z - ((uint32_t)((int32_t)z >> 31) & TWO32_MOD_P);
    return umin32(t, t - P_MOD);
}
// numpy (u + t2) % P, u,t2 in [0,P)
__device__ __forceinline__ uint32_t addmod_w(uint32_t u, uint32_t t2) {
    return wrapmod(u + t2);
}
// numpy (u - t2) % P, u,t2 in [0,P): no int32 overflow possible
__device__ __forceinline__ uint32_t submod_w(uint32_t u, uint32_t t2) {
    uint32_t d = u - t2;
    return umin32(d, d + P_MOD);
}
// numpy int32 (a*b) wrap + % P
__device__ __forceinline__ uint32_t mulmod_wrap(uint32_t a, uint32_t b) {
    return wrapmod(a * b);
}
// in-place butterfly: (u,v) <- (u + v*w, u - v*w), exact wrap semantics
__device__ __forceinline__ void bf_w(uint32_t& u, uint32_t& v, uint32_t w) {
    uint32_t t  = mulmod_wrap(v, w);
    uint32_t nu = addmod_w(u, t);
    v = submod_w(u, t);
    u = nu;
}

// ---- Montgomery (R = 2^32): ONLY to synthesize exact twiddle values ----
__host__ __device__ constexpr uint32_t compute_pinv_neg() {
    uint32_t x = 1u;
    for (int i = 0; i < 5; ++i) x *= (2u - P_MOD * x);
    return 0u - x;                        // -P^{-1} mod 2^32
}
#define PINV_NEG (compute_pinv_neg())
constexpr uint32_t R2_MOD_P = (uint32_t)(((unsigned __int128)1 << 64) % P_MOD);

// montmul(a,b) = a*b*2^{-32} mod P in [0,P).  a in Montgomery form -> exact.
__device__ __forceinline__ uint32_t montmul(uint32_t a, uint32_t b) {
    uint32_t lo = a * b;
    uint32_t hi = __umulhi(a, b);
    uint32_t m  = lo * PINV_NEG;
    uint32_t t  = hi + __umulhi(m, P_MOD) + (lo != 0u);
    return umin32(t, t - P_MOD);
}

// ---- non-temporal 16B load/store ----
typedef uint32_t u32x4 __attribute__((ext_vector_type(4)));
__device__ __forceinline__ uint4 nt_load4(const uint32_t* p) {
    u32x4 v = __builtin_nontemporal_load(reinterpret_cast<const u32x4*>(p));
    return make_uint4(v.x, v.y, v.z, v.w);
}
__device__ __forceinline__ void nt_store4(uint32_t* p, uint4 x) {
    u32x4 v = {x.x, x.y, x.z, x.w};
    __builtin_nontemporal_store(v, reinterpret_cast<u32x4*>(p));
}

// ---------------------------------------------------------------------------
// K0: pack per-stage twiddles for K2 (stages 7..13): stage pa at base
// (2^(pa-1) - 64), ptw[base+j] = twsel[j << (logn-pa)].  8128 words.
// ---------------------------------------------------------------------------
__global__ __launch_bounds__(256) void ntt_pack(
    const uint32_t* __restrict__ tw,
    const uint32_t* __restrict__ itw,
    const int* __restrict__ f_intt,
    uint32_t* __restrict__ ptw, int logn)
{
    int idx = blockIdx.x * 256 + threadIdx.x;
    if (idx >= 8128) return;
    const uint32_t* __restrict__ twsel = f_intt[0] ? itw : tw;
    uint32_t v = (uint32_t)idx + 64u;
    int pm1 = 31 - __clz(v);
    int j   = (int)(v - (1u << pm1));
    int pa  = pm1 + 1;
    ptw[idx] = twsel[(uint32_t)j << (logn - pa)];
}

// ---------------------------------------------------------------------------
// K1: tiled bit-reversal permute + coset pre-scale + stages 1..6 as three
// fused radix-4 pairs (1,2)(3,4)(5,6).  Stage twiddles hoisted to shT[32].
// Lane map row=tid&63 -> every LDS sweep is 2-way max (free).
// ---------------------------------------------------------------------------
__global__ __launch_bounds__(256, 4) void ntt_k1(
    const uint32_t* __restrict__ in,
    const uint32_t* __restrict__ tw,
    const uint32_t* __restrict__ itw,
    const uint32_t* __restrict__ cp,
    const int* __restrict__ f_intt,
    const int* __restrict__ f_coset,
    uint32_t* __restrict__ out,
    int logn)
{
    __shared__ uint32_t sh[64 * 65];      // [u][c], pitch 65: (u+c)%32 banks
    __shared__ uint32_t shT[32];          // shT[k] = twsel[k << (logn-6)]
    const int tid = threadIdx.x;
    const int w   = blockIdx.x;
    const long long base = (long long)blockIdx.y << logn;

    const int is_intt  = f_intt[0];
    const bool do_coset = (!is_intt) && (f_coset[0] != 0);
    const uint32_t* __restrict__ twsel = is_intt ? itw : tw;

    if (tid < 32) shT[tid] = twsel[(uint32_t)tid << (logn - 6)];

    const uint32_t wrev = __brev((uint32_t)w) >> (32 - (logn - 12));

    // gather: uint4/thread; s = 4*s4+k, u = brev6(s) = brev2(k)*16 + brev4(s4)
    const int s4 = tid & 15;
    const uint32_t ub = __brev((uint32_t)s4) >> 28;
    for (int it = 0; it < 4; ++it) {
        int c = (it << 4) | (tid >> 4);
        uint32_t crev = __brev((uint32_t)c) >> 26;
        long long src = ((long long)crev << (logn - 6)) |
                        ((long long)wrev << 6) | (unsigned)(s4 << 2);
        uint4 x = nt_load4(in + base + src);
        if (do_coset) {
            uint4 cv = nt_load4(cp + src);
            x.x = mulmod_wrap(x.x, cv.x);
            x.y = mulmod_wrap(x.y, cv.y);
            x.z = mulmod_wrap(x.z, cv.z);
            x.w = mulmod_wrap(x.w, cv.w);
        }
        sh[(ub     ) * 65 + c] = x.x;
        sh[(ub + 32) * 65 + c] = x.y;
        sh[(ub + 16) * 65 + c] = x.z;
        sh[(ub + 48) * 65 + c] = x.w;
    }
    __syncthreads();

    // fused pairs (pa, pa+1), pa in {1,3,5}: quad {c0, c0+hs, c0+2hs, c0+3hs}
#pragma unroll
    for (int pa = 1; pa <= 5; pa += 2) {
        const int hs = 1 << (pa - 1);
        const int row = tid & 63;
        for (int it = 0; it < 4; ++it) {
            int q    = (tid >> 6) + (it << 2);        // quad index 0..15
            int cj   = q & (hs - 1);
            int cblk = q >> (pa - 1);
            int c0   = (cblk << (pa + 1)) | cj;
            int b    = row * 65 + c0;
            uint32_t e0 = sh[b], e1 = sh[b + hs], e2 = sh[b + 2*hs], e3 = sh[b + 3*hs];
            uint32_t w0 = shT[cj << (6 - pa)];        // stage pa, j=cj (both pairs)
            uint32_t w1 = shT[cj << (5 - pa)];        // stage pa+1, j=cj
            uint32_t w2 = shT[(cj + hs) << (5 - pa)]; // stage pa+1, j=cj+hs
            bf_w(e0, e1, w0);
            bf_w(e2, e3, w0);
            bf_w(e0, e2, w1);
            bf_w(e1, e3, w2);
            sh[b] = e0; sh[b + hs] = e1; sh[b + 2*hs] = e2; sh[b + 3*hs] = e3;
        }
        __syncthreads();
    }

    // scatter: uint4/thread (4 consecutive c, fixed u); cacheable (K2 re-reads)
    for (int it = 0; it < 4; ++it) {
        int u  = (it << 4) | (tid >> 4);
        int cb = (tid & 15) << 2;
        uint4 x;
        x.x = sh[u * 65 + cb    ];
        x.y = sh[u * 65 + cb + 1];
        x.z = sh[u * 65 + cb + 2];
        x.w = sh[u * 65 + cb + 3];
        long long dst = ((long long)u << (logn - 6)) |
                        ((long long)w << 6) | (unsigned)cb;
        *(uint4*)(out + base + dst) = x;
    }
}

// ---------------------------------------------------------------------------
// K2: stages 7..13 on contiguous 8192-blocks. Fused radix-4 rounds (7,8)
// (9,10)(11,12) with quad-j (b128): 16 elements/thread/round; then stage 13.
// Twiddle quads from packed table. 512 threads, 32 KB LDS.
// ---------------------------------------------------------------------------
__global__ __launch_bounds__(512, 4) void ntt_k2(
    const uint32_t* __restrict__ tw,
    const uint32_t* __restrict__ itw,
    const int* __restrict__ f_intt,
    const uint32_t* __restrict__ ptw,
    uint32_t* __restrict__ data,
    int logn)
{
    alignas(16) __shared__ uint32_t sh[8192];
    const int tid = threadIdx.x;
    const long long base = ((long long)blockIdx.y << logn) +
                           ((long long)blockIdx.x << 13);
    const uint32_t* __restrict__ twsel = f_intt[0] ? itw : tw;

    for (int it = 0; it < 4; ++it) {
        int t4 = tid + it * 512;
        ((uint4*)sh)[t4] = nt_load4(data + base + (t4 << 2));
    }
    __syncthreads();

#pragma unroll
    for (int pa = 7; pa <= 11; pa += 2) {
        const int hs  = 1 << (pa - 1);    // 64 / 256 / 1024
        const int pb0 = hs - 64;
        const int pb1 = 2 * hs - 64;
        int q    = tid;                   // 512 items cover all 8192 elements
        int jq   = q & ((hs >> 2) - 1);
        int sblk = q >> (pa - 3);
        int j    = jq << 2;
        int i0   = (sblk << (pa + 1)) | j;
        uint4 e0 = *(const uint4*)&sh[i0];
        uint4 e1 = *(const uint4*)&sh[i0 + hs];
        uint4 e2 = *(const uint4*)&sh[i0 + 2*hs];
        uint4 e3 = *(const uint4*)&sh[i0 + 3*hs];
        uint4 w0, w1a, w1b;
        if (ptw) {
            w0  = *(const uint4*)&ptw[pb0 + j];
            w1a = *(const uint4*)&ptw[pb1 + j];
            w1b = *(const uint4*)&ptw[pb1 + hs + j];
        } else {
            const int t0s = logn - pa, t1s = logn - pa - 1;
            w0  = make_uint4(twsel[(uint32_t)(j)<<t0s], twsel[(uint32_t)(j+1)<<t0s],
                             twsel[(uint32_t)(j+2)<<t0s], twsel[(uint32_t)(j+3)<<t0s]);
            w1a = make_uint4(twsel[(uint32_t)(j)<<t1s], twsel[(uint32_t)(j+1)<<t1s],
                             twsel[(uint32_t)(j+2)<<t1s], twsel[(uint32_t)(j+3)<<t1s]);
            w1b = make_uint4(twsel[(uint32_t)(j+hs)<<t1s], twsel[(uint32_t)(j+hs+1)<<t1s],
                             twsel[(uint32_t)(j+hs+2)<<t1s], twsel[(uint32_t)(j+hs+3)<<t1s]);
        }
        // stage pa: (e0,e1),(e2,e3) both with w0
        bf_w(e0.x, e1.x, w0.x); bf_w(e0.y, e1.y, w0.y);
        bf_w(e0.z, e1.z, w0.z); bf_w(e0.w, e1.w, w0.w);
        bf_w(e2.x, e3.x, w0.x); bf_w(e2.y, e3.y, w0.y);
        bf_w(e2.z, e3.z, w0.z); bf_w(e2.w, e3.w, w0.w);
        // stage pa+1: (e0,e2) w1a, (e1,e3) w1b
        bf_w(e0.x, e2.x, w1a.x); bf_w(e0.y, e2.y, w1a.y);
        bf_w(e0.z, e2.z, w1a.z); bf_w(e0.w, e2.w, w1a.w);
        bf_w(e1.x, e3.x, w1b.x); bf_w(e1.y, e3.y, w1b.y);
        bf_w(e1.z, e3.z, w1b.z); bf_w(e1.w, e3.w, w1b.w);
        *(uint4*)&sh[i0         ] = e0;
        *(uint4*)&sh[i0 +   hs  ] = e1;
        *(uint4*)&sh[i0 + 2*hs  ] = e2;
        *(uint4*)&sh[i0 + 3*hs  ] = e3;
        __syncthreads();
    }

    // stage 13 (hs = 4096), quad butterflies
    {
        const int hs = 4096, pb = hs - 64;
        for (int it = 0; it < 2; ++it) {
            int j  = (tid + it * 512) << 2;
            uint4 u = *(const uint4*)&sh[j];
            uint4 v = *(const uint4*)&sh[j + hs];
            uint4 wv;
            if (ptw) wv = *(const uint4*)&ptw[pb + j];
            else {
                const int ts = logn - 13;
                wv = make_uint4(twsel[(uint32_t)(j)<<ts], twsel[(uint32_t)(j+1)<<ts],
                                twsel[(uint32_t)(j+2)<<ts], twsel[(uint32_t)(j+3)<<ts]);
            }
            bf_w(u.x, v.x, wv.x); bf_w(u.y, v.y, wv.y);
            bf_w(u.z, v.z, wv.z); bf_w(u.w, v.w, wv.w);
            *(uint4*)&sh[j] = u;
            *(uint4*)&sh[j + hs] = v;
        }
        __syncthreads();
    }

    for (int it = 0; it < 4; ++it) {
        int t4 = tid + it * 512;
        ((uint4*)(data + base))[t4] = ((const uint4*)sh)[t4];
    }
}

// ---------------------------------------------------------------------------
// K3: stages 14..22 (local p=0..8) as three fused radix-8 triples (0-2)(3-5)
// (6-8). Tile: 512 strided (stride 2^13) x 32 lows. Twiddles synthesized:
// w(sj,lo,p) = montmul(shA[2^p-1+sj], shB[p][lo]) — 7 per octet (12 bf).
// ---------------------------------------------------------------------------
__global__ __launch_bounds__(1024, 4) void ntt_k3(
    const uint32_t* __restrict__ tw,
    const uint32_t* __restrict__ itw,
    const uint32_t* __restrict__ icp,
    const int* __restrict__ f_intt,
    const int* __restrict__ f_coset,
    uint32_t* __restrict__ data,
    uint32_t ninv, int logn)
{
    alignas(16) __shared__ uint32_t sh[512 * 32];
    alignas(16) __shared__ uint32_t shB[9 * 32];  // wB[p][lo], plain form
    __shared__ uint32_t shA[511];                 // wA Montgomery form, base 2^p-1
    const int tid = threadIdx.x;
    const long long base = (long long)blockIdx.y << logn;
    const int lowbase = blockIdx.x * 32;

    const int is_intt  = f_intt[0];
    const int is_coset = f_coset[0];
    const uint32_t* __restrict__ twsel = is_intt ? itw : tw;

    if (tid < 511) {
        uint32_t v = (uint32_t)tid + 1u;
        int p  = 31 - __clz(v);
        int sj = (int)(v - (1u << p));
        shA[tid] = montmul(twsel[(uint32_t)sj << (21 - p)], R2_MOD_P);
    } else if (tid >= 512 && tid < 512 + 288) {
        int k = tid - 512, p = k >> 5, lo = k & 31;
        shB[k] = twsel[(uint32_t)(lowbase + lo) << (8 - p)];
    }

    for (int it = 0; it < 4; ++it) {
        int e4  = tid + it * 1024;
        int lo4 = e4 & 7;
        int s   = e4 >> 3;
        uint4 x = nt_load4(data + base + ((long long)s << 13) + lowbase + (lo4 << 2));
        *(uint4*)&sh[(s << 5) | (lo4 << 2)] = x;
    }
    __syncthreads();

#pragma unroll
    for (int p = 0; p <= 6; p += 3) {
        const int hs = 1 << p;            // 1 / 8 / 64
        for (int it = 0; it < 2; ++it) {
            int wi = tid + it * 1024;     // 0..2047 = 64 s-octets x 32 lows
            int lo = wi & 31;
            int sq = wi >> 5;             // 0..63
            int sj = sq & (hs - 1);
            int sblk = sq >> p;
            int s0 = (sblk << (p + 3)) | sj;
            int b  = (s0 << 5) | lo;
            const int st = hs << 5;       // LDS step between octet members
            uint32_t e0 = sh[b        ], e1 = sh[b +   st],
                     e2 = sh[b + 2*st], e3 = sh[b + 3*st],
                     e4 = sh[b + 4*st], e5 = sh[b + 5*st],
                     e6 = sh[b + 6*st], e7 = sh[b + 7*st];
            uint32_t b0 = shB[((p    ) << 5) | lo];
            uint32_t b1 = shB[((p + 1) << 5) | lo];
            uint32_t b2 = shB[((p + 2) << 5) | lo];
            uint32_t tw0  = montmul(shA[(    hs - 1) + sj         ], b0);
            uint32_t tw1a = montmul(shA[(2 * hs - 1) + sj         ], b1);
            uint32_t tw1b = montmul(shA[(2 * hs - 1) + sj +     hs], b1);
            uint32_t tw2a = montmul(shA[(4 * hs - 1) + sj         ], b2);
            uint32_t tw2b = montmul(shA[(4 * hs - 1) + sj +     hs], b2);
            uint32_t tw2c = montmul(shA[(4 * hs - 1) + sj + 2 * hs], b2);
            uint32_t tw2d = montmul(shA[(4 * hs - 1) + sj + 3 * hs], b2);
            // stage p
            bf_w(e0, e1, tw0); bf_w(e2, e3, tw0);
            bf_w(e4, e5, tw0); bf_w(e6, e7, tw0);
            // stage p+1
            bf_w(e0, e2, tw1a); bf_w(e1, e3, tw1b);
            bf_w(e4, e6, tw1a); bf_w(e5, e7, tw1b);
            // stage p+2
            bf_w(e0, e4, tw2a); bf_w(e1, e5, tw2b);
            bf_w(e2, e6, tw2c); bf_w(e3, e7, tw2d);
            sh[b        ] = e0; sh[b +   st] = e1;
            sh[b + 2*st] = e2; sh[b + 3*st] = e3;
            sh[b + 4*st] = e4; sh[b + 5*st] = e5;
            sh[b + 6*st] = e6; sh[b + 7*st] = e7;
        }
        __syncthreads();
    }

    // store (+ INTT post-scales, wrap-correct); final output non-temporal
    for (int it = 0; it < 4; ++it) {
        int e4  = tid + it * 1024;
        int lo4 = e4 & 7;
        int s   = e4 >> 3;
        uint4 val = *(const uint4*)&sh[(s << 5) | (lo4 << 2)];
        long long gi = ((long long)s << 13) + lowbase + (lo4 << 2);
        if (is_intt) {
            val.x = mulmod_wrap(val.x, ninv);
            val.y = mulmod_wrap(val.y, ninv);
            val.z = mulmod_wrap(val.z, ninv);
            val.w = mulmod_wrap(val.w, ninv);
            if (is_coset) {
                uint4 ic = *(const uint4*)(icp + gi);
                val.x = mulmod_wrap(val.x, ic.x);
                val.y = mulmod_wrap(val.y, ic.y);
                val.z = mulmod_wrap(val.z, ic.z);
                val.w = mulmod_wrap(val.w, ic.w);
            }
        }
        nt_store4(data + base + gi, val);
    }
}

extern "C" void kernel_launch(void* const* d_in, const int* in_sizes, int n_in,
                              void* d_out, int out_size, void* d_ws, size_t ws_size,
                              hipStream_t stream) {
    const uint32_t* in  = (const uint32_t*)d_in[0];
    const uint32_t* tw  = (const uint32_t*)d_in[1];
    const uint32_t* itw = (const uint32_t*)d_in[2];
    const uint32_t* cp  = (const uint32_t*)d_in[3];
    const uint32_t* icp = (const uint32_t*)d_in[4];
    const int* f_intt  = (const int*)d_in[6];
    const int* f_coset = (const int*)d_in[7];

    const int N = in_sizes[5];
    const int B = in_sizes[0] / N;
    int logn = 0; while ((1 << logn) < N) ++logn;

    const unsigned long long P = 2013265921ull;
    unsigned long long b = (unsigned long long)N % P, e = P - 2, acc = 1;
    while (e) { if (e & 1) acc = acc * b % P; b = b * b % P; e >>= 1; }
    const uint32_t ninv = (uint32_t)acc;

    uint32_t* out = (uint32_t*)d_out;

    uint32_t* ptw = (ws_size >= 8128u * 4u) ? (uint32_t*)d_ws : nullptr;
    if (ptw) ntt_pack<<<dim3(32), dim3(256), 0, stream>>>(tw, itw, f_intt, ptw, logn);

    dim3 g1(N / 4096, B);
    ntt_k1<<<g1, dim3(256), 0, stream>>>(in, tw, itw, cp, f_intt, f_coset, out, logn);

    dim3 g2(N / 8192, B);
    ntt_k2<<<g2, dim3(512), 0, stream>>>(tw, itw, f_intt, ptw, out, logn);

    dim3 g3(8192 / 32, B);
    ntt_k3<<<g3, dim3(1024), 0, stream>>>(tw, itw, icp, f_intt, f_coset, out, ninv, logn);
}

// Round 5
// 449.528 us; speedup vs baseline: 2.6221x; 1.0500x over previous
//
#include <hip/hip_runtime.h>
#include <stdint.h>

#define P_MOD       2013265921u   // 15*2^27 + 1
#define TWO32_MOD_P 268435454u    // 2^32 mod P == 2^32 - 2P

__device__ __forceinline__ uint32_t umin32(uint32_t a, uint32_t b) { return a < b ? a : b; }

// W(z): least nonneg residue mod P of int32-interpretation of z (numpy int32
// wrap + numpy `% P`).  t = z - sign*(2^32-2P) lands in [0,2P); one cond-sub.
__device__ __forceinline__ uint32_t wrapmod(uint32_t z) {
    uint32_t t = z - ((uint32_t)((int32_t)z >> 31) & TWO32_MOD_P);
    return umin32(t, t - P_MOD);
}
__device__ __forceinline__ uint32_t addmod_w(uint32_t u, uint32_t t2) {
    return wrapmod(u + t2);
}
__device__ __forceinline__ uint32_t submod_w(uint32_t u, uint32_t t2) {
    uint32_t d = u - t2;
    return umin32(d, d + P_MOD);
}
__device__ __forceinline__ uint32_t mulmod_wrap(uint32_t a, uint32_t b) {
    return wrapmod(a * b);
}
// in-place butterfly: (u,v) <- (u + v*w, u - v*w), exact wrap semantics
__device__ __forceinline__ void bf_w(uint32_t& u, uint32_t& v, uint32_t w) {
    uint32_t t  = mulmod_wrap(v, w);
    uint32_t nu = addmod_w(u, t);
    v = submod_w(u, t);
    u = nu;
}

// ---- Montgomery (R = 2^32): ONLY to synthesize exact twiddle/coset values ----
__host__ __device__ constexpr uint32_t compute_pinv_neg() {
    uint32_t x = 1u;
    for (int i = 0; i < 5; ++i) x *= (2u - P_MOD * x);
    return 0u - x;                        // -P^{-1} mod 2^32
}
#define PINV_NEG (compute_pinv_neg())
constexpr uint32_t R2_MOD_P = (uint32_t)(((unsigned __int128)1 << 64) % P_MOD);

// montmul(a,b) = a*b*2^{-32} mod P in [0,P).  a in Montgomery form -> exact.
__device__ __forceinline__ uint32_t montmul(uint32_t a, uint32_t b) {
    uint32_t lo = a * b;
    uint32_t hi = __umulhi(a, b);
    uint32_t m  = lo * PINV_NEG;
    uint32_t t  = hi + __umulhi(m, P_MOD) + (lo != 0u);
    return umin32(t, t - P_MOD);
}

// ---- non-temporal 16B load/store ----
typedef uint32_t u32x4 __attribute__((ext_vector_type(4)));
__device__ __forceinline__ uint4 nt_load4(const uint32_t* p) {
    u32x4 v = __builtin_nontemporal_load(reinterpret_cast<const u32x4*>(p));
    return make_uint4(v.x, v.y, v.z, v.w);
}
__device__ __forceinline__ void nt_store4(uint32_t* p, uint4 x) {
    u32x4 v = {x.x, x.y, x.z, x.w};
    __builtin_nontemporal_store(v, reinterpret_cast<u32x4*>(p));
}

// ---------------------------------------------------------------------------
// K1: tiled bit-reversal permute + coset pre-scale + stages 1..6 as three
// fused radix-4 pairs.  Coset factors SYNTHESIZED (no 134 MB cp stream):
//   cp[src] = cp[crev<<16] * cp[wrev<<6] * cp[s]  (exact via montmul tables).
// Block (0,0) additionally packs the K2 twiddle table into ptw (workspace);
// stream order guarantees it completes before K2 launches.
// ---------------------------------------------------------------------------
__global__ __launch_bounds__(256, 4) void ntt_k1(
    const uint32_t* __restrict__ in,
    const uint32_t* __restrict__ tw,
    const uint32_t* __restrict__ itw,
    const uint32_t* __restrict__ cp,
    const int* __restrict__ f_intt,
    const int* __restrict__ f_coset,
    uint32_t* __restrict__ out,
    uint32_t* __restrict__ ptw,
    int logn)
{
    __shared__ uint32_t sh[64 * 65];      // [u][c], pitch 65: butterflies 2-way max
    __shared__ uint32_t shT[32];          // stage twiddles: twsel[k << (logn-6)]
    __shared__ uint32_t shG1[64];                       // mont(cp[brev6(c)<<16])
    alignas(16) __shared__ uint32_t shGW[64];           // cp[wrev<<6]*cp[s] mod P
    const int tid = threadIdx.x;
    const int w   = blockIdx.x;
    const long long base = (long long)blockIdx.y << logn;

    const int is_intt  = f_intt[0];
    const bool do_coset = (!is_intt) && (f_coset[0] != 0);
    const uint32_t* __restrict__ twsel = is_intt ? itw : tw;

    const uint32_t wrev = __brev((uint32_t)w) >> (32 - (logn - 12));

    // cooperative table build (disjoint thread ranges)
    if (tid < 32) {
        shT[tid] = twsel[(uint32_t)tid << (logn - 6)];
    } else if (tid >= 128 && tid < 192) {
        int m = tid - 128;
        uint32_t t1 = cp[(long long)(__brev((uint32_t)m) >> 26) << (logn - 6)];
        shG1[m] = montmul(t1, R2_MOD_P);              // Montgomery form
    } else if (tid >= 192) {
        int s = tid - 192;
        uint32_t mgw = montmul(cp[(uint32_t)wrev << 6], R2_MOD_P);
        shGW[s] = montmul(mgw, cp[s]);                // plain form, in [0,P)
    }
    __syncthreads();

    // gather: uint4/thread; s = 4*s4+k, u = brev6(s) = brev2(k)*16 + brev4(s4)
    const int s4 = tid & 15;
    const uint32_t ub = __brev((uint32_t)s4) >> 28;
    for (int it = 0; it < 4; ++it) {
        int c = (it << 4) | (tid >> 4);
        uint32_t crev = __brev((uint32_t)c) >> 26;
        long long src = ((long long)crev << (logn - 6)) |
                        ((long long)wrev << 6) | (unsigned)(s4 << 2);
        uint4 x = nt_load4(in + base + src);
        if (do_coset) {
            uint32_t mg1 = shG1[c];
            uint4 g = *(const uint4*)&shGW[s4 << 2];
            x.x = mulmod_wrap(x.x, montmul(mg1, g.x));
            x.y = mulmod_wrap(x.y, montmul(mg1, g.y));
            x.z = mulmod_wrap(x.z, montmul(mg1, g.z));
            x.w = mulmod_wrap(x.w, montmul(mg1, g.w));
        }
        sh[(ub     ) * 65 + c] = x.x;
        sh[(ub + 32) * 65 + c] = x.y;
        sh[(ub + 16) * 65 + c] = x.z;
        sh[(ub + 48) * 65 + c] = x.w;
    }
    __syncthreads();

    // fused pairs (pa, pa+1), pa in {1,3,5}
#pragma unroll
    for (int pa = 1; pa <= 5; pa += 2) {
        const int hs = 1 << (pa - 1);
        const int row = tid & 63;
        for (int it = 0; it < 4; ++it) {
            int q    = (tid >> 6) + (it << 2);        // quad index 0..15
            int cj   = q & (hs - 1);
            int cblk = q >> (pa - 1);
            int c0   = (cblk << (pa + 1)) | cj;
            int b    = row * 65 + c0;
            uint32_t e0 = sh[b], e1 = sh[b + hs], e2 = sh[b + 2*hs], e3 = sh[b + 3*hs];
            uint32_t w0 = shT[cj << (6 - pa)];
            uint32_t w1 = shT[cj << (5 - pa)];
            uint32_t w2 = shT[(cj + hs) << (5 - pa)];
            bf_w(e0, e1, w0);
            bf_w(e2, e3, w0);
            bf_w(e0, e2, w1);
            bf_w(e1, e3, w2);
            sh[b] = e0; sh[b + hs] = e1; sh[b + 2*hs] = e2; sh[b + 3*hs] = e3;
        }
        __syncthreads();
    }

    // scatter: uint4/thread (4 consecutive c, fixed u); cacheable (K2 re-reads)
    for (int it = 0; it < 4; ++it) {
        int u  = (it << 4) | (tid >> 4);
        int cb = (tid & 15) << 2;
        uint4 x;
        x.x = sh[u * 65 + cb    ];
        x.y = sh[u * 65 + cb + 1];
        x.z = sh[u * 65 + cb + 2];
        x.w = sh[u * 65 + cb + 3];
        long long dst = ((long long)u << (logn - 6)) |
                        ((long long)w << 6) | (unsigned)cb;
        *(uint4*)(out + base + dst) = x;
    }

    // fold-in of the old pack kernel: block (0,0) fills ptw for K2.
    // stage pa at base (2^(pa-1)-64): ptw[i] = twsel[j << (logn-pa)]
    if (ptw && blockIdx.x == 0 && blockIdx.y == 0) {
        for (int i = tid; i < 8128; i += 256) {
            uint32_t v = (uint32_t)i + 64u;
            int pm1 = 31 - __clz(v);
            int j   = (int)(v - (1u << pm1));
            ptw[i] = twsel[(uint32_t)j << (logn - pm1 - 1)];
        }
    }
}

// ---------------------------------------------------------------------------
// K2: stages 7..13 on contiguous 8192-blocks, fused radix-4 rounds (7,8)
// (9,10)(11,12) + stage 13.  Twiddle quads PREFETCHED one round ahead into
// registers so the L2 loads overlap the previous round's compute (removes
// the post-barrier lockstep stall seen at VALUBusy=47%).
// ---------------------------------------------------------------------------
__global__ __launch_bounds__(512, 4) void ntt_k2(
    const uint32_t* __restrict__ tw,
    const uint32_t* __restrict__ itw,
    const int* __restrict__ f_intt,
    const uint32_t* __restrict__ ptw,
    uint32_t* __restrict__ data,
    int logn)
{
    alignas(16) __shared__ uint32_t sh[8192];
    const int tid = threadIdx.x;
    const long long base = ((long long)blockIdx.y << logn) +
                           ((long long)blockIdx.x << 13);
    const uint32_t* __restrict__ twsel = f_intt[0] ? itw : tw;

    // prefetch round (7,8) twiddles
    uint4 w0, w1a, w1b;
    {
        const int j = (tid & 15) << 2;
        if (ptw) {
            w0  = *(const uint4*)&ptw[j];
            w1a = *(const uint4*)&ptw[64 + j];
            w1b = *(const uint4*)&ptw[128 + j];
        } else {
            const int t0s = logn - 7, t1s = logn - 8;
            w0  = make_uint4(twsel[(uint32_t)(j)<<t0s], twsel[(uint32_t)(j+1)<<t0s],
                             twsel[(uint32_t)(j+2)<<t0s], twsel[(uint32_t)(j+3)<<t0s]);
            w1a = make_uint4(twsel[(uint32_t)(j)<<t1s], twsel[(uint32_t)(j+1)<<t1s],
                             twsel[(uint32_t)(j+2)<<t1s], twsel[(uint32_t)(j+3)<<t1s]);
            w1b = make_uint4(twsel[(uint32_t)(j+64)<<t1s], twsel[(uint32_t)(j+65)<<t1s],
                             twsel[(uint32_t)(j+66)<<t1s], twsel[(uint32_t)(j+67)<<t1s]);
        }
    }

    for (int it = 0; it < 4; ++it) {
        int t4 = tid + it * 512;
        ((uint4*)sh)[t4] = nt_load4(data + base + (t4 << 2));
    }
    __syncthreads();

#pragma unroll
    for (int pa = 7; pa <= 11; pa += 2) {
        const int hs = 1 << (pa - 1);     // 64 / 256 / 1024
        // prefetch next round's twiddles (completes during this round)
        uint4 n0, n1a, n1b;
        if (pa < 11) {
            const int hsn = hs << 2;
            const int jn  = (tid & ((hsn >> 2) - 1)) << 2;
            if (ptw) {
                n0  = *(const uint4*)&ptw[(hsn - 64) + jn];
                n1a = *(const uint4*)&ptw[(2*hsn - 64) + jn];
                n1b = *(const uint4*)&ptw[(2*hsn - 64) + hsn + jn];
            } else {
                const int t0s = logn - pa - 2, t1s = logn - pa - 3;
                n0  = make_uint4(twsel[(uint32_t)(jn)<<t0s], twsel[(uint32_t)(jn+1)<<t0s],
                                 twsel[(uint32_t)(jn+2)<<t0s], twsel[(uint32_t)(jn+3)<<t0s]);
                n1a = make_uint4(twsel[(uint32_t)(jn)<<t1s], twsel[(uint32_t)(jn+1)<<t1s],
                                 twsel[(uint32_t)(jn+2)<<t1s], twsel[(uint32_t)(jn+3)<<t1s]);
                n1b = make_uint4(twsel[(uint32_t)(jn+hsn)<<t1s], twsel[(uint32_t)(jn+hsn+1)<<t1s],
                                 twsel[(uint32_t)(jn+hsn+2)<<t1s], twsel[(uint32_t)(jn+hsn+3)<<t1s]);
            }
        } else {
            const int j1 = tid << 2, j2 = (tid + 512) << 2;
            if (ptw) {
                n0  = *(const uint4*)&ptw[4032 + j1];
                n1a = *(const uint4*)&ptw[4032 + j2];
            } else {
                const int ts = logn - 13;
                n0  = make_uint4(twsel[(uint32_t)(j1)<<ts], twsel[(uint32_t)(j1+1)<<ts],
                                 twsel[(uint32_t)(j1+2)<<ts], twsel[(uint32_t)(j1+3)<<ts]);
                n1a = make_uint4(twsel[(uint32_t)(j2)<<ts], twsel[(uint32_t)(j2+1)<<ts],
                                 twsel[(uint32_t)(j2+2)<<ts], twsel[(uint32_t)(j2+3)<<ts]);
            }
            n1b = n0;                     // unused in the tail
        }

        const int jq   = tid & ((hs >> 2) - 1);
        const int sblk = tid >> (pa - 3);
        const int j    = jq << 2;
        const int i0   = (sblk << (pa + 1)) | j;
        uint4 e0 = *(const uint4*)&sh[i0];
        uint4 e1 = *(const uint4*)&sh[i0 + hs];
        uint4 e2 = *(const uint4*)&sh[i0 + 2*hs];
        uint4 e3 = *(const uint4*)&sh[i0 + 3*hs];
        // stage pa: (e0,e1),(e2,e3) both with w0
        bf_w(e0.x, e1.x, w0.x); bf_w(e0.y, e1.y, w0.y);
        bf_w(e0.z, e1.z, w0.z); bf_w(e0.w, e1.w, w0.w);
        bf_w(e2.x, e3.x, w0.x); bf_w(e2.y, e3.y, w0.y);
        bf_w(e2.z, e3.z, w0.z); bf_w(e2.w, e3.w, w0.w);
        // stage pa+1: (e0,e2) w1a, (e1,e3) w1b
        bf_w(e0.x, e2.x, w1a.x); bf_w(e0.y, e2.y, w1a.y);
        bf_w(e0.z, e2.z, w1a.z); bf_w(e0.w, e2.w, w1a.w);
        bf_w(e1.x, e3.x, w1b.x); bf_w(e1.y, e3.y, w1b.y);
        bf_w(e1.z, e3.z, w1b.z); bf_w(e1.w, e3.w, w1b.w);
        *(uint4*)&sh[i0         ] = e0;
        *(uint4*)&sh[i0 +   hs  ] = e1;
        *(uint4*)&sh[i0 + 2*hs  ] = e2;
        *(uint4*)&sh[i0 + 3*hs  ] = e3;
        __syncthreads();
        w0 = n0; w1a = n1a; w1b = n1b;
    }

    // stage 13 (hs=4096): two quads, twiddles already in w0 / w1a
    {
        const int hs = 4096;
        int j = tid << 2;
        uint4 u = *(const uint4*)&sh[j];
        uint4 v = *(const uint4*)&sh[j + hs];
        bf_w(u.x, v.x, w0.x); bf_w(u.y, v.y, w0.y);
        bf_w(u.z, v.z, w0.z); bf_w(u.w, v.w, w0.w);
        *(uint4*)&sh[j] = u;
        *(uint4*)&sh[j + hs] = v;
        j = (tid + 512) << 2;
        uint4 u2 = *(const uint4*)&sh[j];
        uint4 v2 = *(const uint4*)&sh[j + hs];
        bf_w(u2.x, v2.x, w1a.x); bf_w(u2.y, v2.y, w1a.y);
        bf_w(u2.z, v2.z, w1a.z); bf_w(u2.w, v2.w, w1a.w);
        *(uint4*)&sh[j] = u2;
        *(uint4*)&sh[j + hs] = v2;
    }
    __syncthreads();

    for (int it = 0; it < 4; ++it) {
        int t4 = tid + it * 512;
        ((uint4*)(data + base))[t4] = ((const uint4*)sh)[t4];
    }
}

// ---------------------------------------------------------------------------
// K3: stages 14..22 (local p=0..8) as three fused radix-8 triples.
// Tile: 512 strided (stride 2^13) x 32 lows.  Twiddles synthesized:
// w(sj,lo,p) = montmul(shA[2^p-1+sj], shB[p][lo]) — 7 per octet (12 bf).
// ---------------------------------------------------------------------------
__global__ __launch_bounds__(1024, 4) void ntt_k3(
    const uint32_t* __restrict__ tw,
    const uint32_t* __restrict__ itw,
    const uint32_t* __restrict__ icp,
    const int* __restrict__ f_intt,
    const int* __restrict__ f_coset,
    uint32_t* __restrict__ data,
    uint32_t ninv, int logn)
{
    alignas(16) __shared__ uint32_t sh[512 * 32];
    alignas(16) __shared__ uint32_t shB[9 * 32];  // wB[p][lo], plain form
    __shared__ uint32_t shA[511];                 // wA Montgomery form, base 2^p-1
    const int tid = threadIdx.x;
    const long long base = (long long)blockIdx.y << logn;
    const int lowbase = blockIdx.x * 32;

    const int is_intt  = f_intt[0];
    const int is_coset = f_coset[0];
    const uint32_t* __restrict__ twsel = is_intt ? itw : tw;

    if (tid < 511) {
        uint32_t v = (uint32_t)tid + 1u;
        int p  = 31 - __clz(v);
        int sj = (int)(v - (1u << p));
        shA[tid] = montmul(twsel[(uint32_t)sj << (21 - p)], R2_MOD_P);
    } else if (tid >= 512 && tid < 512 + 288) {
        int k = tid - 512, p = k >> 5, lo = k & 31;
        shB[k] = twsel[(uint32_t)(lowbase + lo) << (8 - p)];
    }

    for (int it = 0; it < 4; ++it) {
        int e4  = tid + it * 1024;
        int lo4 = e4 & 7;
        int s   = e4 >> 3;
        uint4 x = nt_load4(data + base + ((long long)s << 13) + lowbase + (lo4 << 2));
        *(uint4*)&sh[(s << 5) | (lo4 << 2)] = x;
    }
    __syncthreads();

#pragma unroll
    for (int p = 0; p <= 6; p += 3) {
        const int hs = 1 << p;            // 1 / 8 / 64
        for (int it = 0; it < 2; ++it) {
            int wi = tid + it * 1024;     // 0..2047 = 64 s-octets x 32 lows
            int lo = wi & 31;
            int sq = wi >> 5;
            int sj = sq & (hs - 1);
            int sblk = sq >> p;
            int s0 = (sblk << (p + 3)) | sj;
            int b  = (s0 << 5) | lo;
            const int st = hs << 5;
            uint32_t e0 = sh[b        ], e1 = sh[b +   st],
                     e2 = sh[b + 2*st], e3 = sh[b + 3*st],
                     e4 = sh[b + 4*st], e5 = sh[b + 5*st],
                     e6 = sh[b + 6*st], e7 = sh[b + 7*st];
            uint32_t b0 = shB[((p    ) << 5) | lo];
            uint32_t b1 = shB[((p + 1) << 5) | lo];
            uint32_t b2 = shB[((p + 2) << 5) | lo];
            uint32_t tw0  = montmul(shA[(    hs - 1) + sj         ], b0);
            uint32_t tw1a = montmul(shA[(2 * hs - 1) + sj         ], b1);
            uint32_t tw1b = montmul(shA[(2 * hs - 1) + sj +     hs], b1);
            uint32_t tw2a = montmul(shA[(4 * hs - 1) + sj         ], b2);
            uint32_t tw2b = montmul(shA[(4 * hs - 1) + sj +     hs], b2);
            uint32_t tw2c = montmul(shA[(4 * hs - 1) + sj + 2 * hs], b2);
            uint32_t tw2d = montmul(shA[(4 * hs - 1) + sj + 3 * hs], b2);
            bf_w(e0, e1, tw0); bf_w(e2, e3, tw0);
            bf_w(e4, e5, tw0); bf_w(e6, e7, tw0);
            bf_w(e0, e2, tw1a); bf_w(e1, e3, tw1b);
            bf_w(e4, e6, tw1a); bf_w(e5, e7, tw1b);
            bf_w(e0, e4, tw2a); bf_w(e1, e5, tw2b);
            bf_w(e2, e6, tw2c); bf_w(e3, e7, tw2d);
            sh[b        ] = e0; sh[b +   st] = e1;
            sh[b + 2*st] = e2; sh[b + 3*st] = e3;
            sh[b + 4*st] = e4; sh[b + 5*st] = e5;
            sh[b + 6*st] = e6; sh[b + 7*st] = e7;
        }
        __syncthreads();
    }

    for (int it = 0; it < 4; ++it) {
        int e4  = tid + it * 1024;
        int lo4 = e4 & 7;
        int s   = e4 >> 3;
        uint4 val = *(const uint4*)&sh[(s << 5) | (lo4 << 2)];
        long long gi = ((long long)s << 13) + lowbase + (lo4 << 2);
        if (is_intt) {
            val.x = mulmod_wrap(val.x, ninv);
            val.y = mulmod_wrap(val.y, ninv);
            val.z = mulmod_wrap(val.z, ninv);
            val.w = mulmod_wrap(val.w, ninv);
            if (is_coset) {
                uint4 ic = *(const uint4*)(icp + gi);
                val.x = mulmod_wrap(val.x, ic.x);
                val.y = mulmod_wrap(val.y, ic.y);
                val.z = mulmod_wrap(val.z, ic.z);
                val.w = mulmod_wrap(val.w, ic.w);
            }
        }
        nt_store4(data + base + gi, val);
    }
}

extern "C" void kernel_launch(void* const* d_in, const int* in_sizes, int n_in,
                              void* d_out, int out_size, void* d_ws, size_t ws_size,
                              hipStream_t stream) {
    const uint32_t* in  = (const uint32_t*)d_in[0];
    const uint32_t* tw  = (const uint32_t*)d_in[1];
    const uint32_t* itw = (const uint32_t*)d_in[2];
    const uint32_t* cp  = (const uint32_t*)d_in[3];
    const uint32_t* icp = (const uint32_t*)d_in[4];
    const int* f_intt  = (const int*)d_in[6];
    const int* f_coset = (const int*)d_in[7];

    const int N = in_sizes[5];
    const int B = in_sizes[0] / N;
    int logn = 0; while ((1 << logn) < N) ++logn;

    const unsigned long long P = 2013265921ull;
    unsigned long long b = (unsigned long long)N % P, e = P - 2, acc = 1;
    while (e) { if (e & 1) acc = acc * b % P; b = b * b % P; e >>= 1; }
    const uint32_t ninv = (uint32_t)acc;

    uint32_t* out = (uint32_t*)d_out;
    uint32_t* ptw = (ws_size >= 8128u * 4u) ? (uint32_t*)d_ws : nullptr;

    dim3 g1(N / 4096, B);
    ntt_k1<<<g1, dim3(256), 0, stream>>>(in, tw, itw, cp, f_intt, f_coset, out, ptw, logn);

    dim3 g2(N / 8192, B);
    ntt_k2<<<g2, dim3(512), 0, stream>>>(tw, itw, f_intt, ptw, out, logn);

    dim3 g3(8192 / 32, B);
    ntt_k3<<<g3, dim3(1024), 0, stream>>>(tw, itw, icp, f_intt, f_coset, out, ninv, logn);
}